// Round 11
// baseline (6118.076 us; speedup 1.0000x reference)
//
#include <hip/hip_runtime.h>

// ---------------------------------------------------------------------------
// LSTM autoregressive, MI355X. Round 11: 2 blocks/CU latency hiding.
//  - grid 512 x 512 threads, BM=16, __launch_bounds__(512,4) -> <=128 VGPR,
//    2 blocks/CU co-resident (LDS 28.5KB x2, VGPR 4 waves/SIMD exact)
//  - lockstep L2 weight sharing kept (r10: FETCH 9.8GB -> 16.6MB), pacing
//    barrier relaxed to every 2nd step (halve straggler/atomic overhead)
//  - hi-only B streamed 1-deep, 2-product fp16 split, numerics = r5-r10
// ---------------------------------------------------------------------------

typedef _Float16 f16;
typedef _Float16 f16x4 __attribute__((ext_vector_type(4)));
typedef _Float16 f16x8 __attribute__((ext_vector_type(8)));
typedef float    f32x4 __attribute__((ext_vector_type(4)));

#define MFMA16(a,b,c) __builtin_amdgcn_mfma_f32_16x16x32_f16((a),(b),(c),0,0,0)

#define BM 16     // batch rows per block
#define NBLK 512  // grid size (2 blocks/CU, co-resident -> barrier safe)

// ws layout: fp16 B-hi fragments (halves), then fp32 region (floats)
#define HOFF_E0 0        // enc L0: KT=5, NT=32  (k: [Whh 128 | Wih 6 | pad])
#define HOFF_E1 81920    // enc L1: KT=8, NT=32  (k: [Wih 128 | Whh 128])
#define HOFF_D0 212992   // dec L0: KT=5, NT=32  (k: [Whh 128 | Wih 2 | pad])
#define HOFF_D1 294912   // dec L1: KT=8, NT=32
#define HOFF_H  425984   // head W1: KT=4, NT=8
#define H_TOTAL 442368
#define FOFF    221184   // float offset of fp32 region (= H_TOTAL/2)
#define FB_E0 0
#define FB_E1 512
#define FB_D0 1024
#define FB_D1 1536
#define FB_H1 2048
#define FB_W2 2176
#define FB_B2 2432
#define F_TOTAL 2434
#define BAR_F   2560     // barrier counters at float offset 2560 (128 used)
#define BAR_BYTES 1024

#define A1S 172   // A1 row stride (halves)
#define A2S 140   // A2 row stride (halves)
#define O1S 133   // o1 row stride (floats)

__device__ __forceinline__ float fsig(float x){ return 1.0f/(1.0f+__expf(-x)); }
__device__ __forceinline__ float ftanh(float x){
  float a = fabsf(x);
  float e = __expf(-2.0f*a);
  float t = (1.0f-e)/(1.0f+e);
  return x < 0.0f ? -t : t;
}

// pacing barrier: pure performance device (lockstep weight streaming);
// correctness does not depend on it. One counter per pace event.
__device__ __forceinline__ void grid_pace(unsigned* __restrict__ bar, int idx, int tid){
  __syncthreads();
  if (tid == 0){
    __hip_atomic_fetch_add(&bar[idx], 1u, __ATOMIC_RELAXED, __HIP_MEMORY_SCOPE_AGENT);
    while (__hip_atomic_load(&bar[idx], __ATOMIC_RELAXED, __HIP_MEMORY_SCOPE_AGENT) < (unsigned)NBLK)
      __builtin_amdgcn_s_sleep(1);
  }
  __syncthreads();
}

// A fragment: row = lane&15; k = kc + (lane>>4)*4 + j (+16 for j>=4)
template<int STRIDE>
__device__ __forceinline__ f16x8 load_afrag(const f16* buf, int kc, int lane){
  const f16* p = buf + (lane&15)*STRIDE + kc + ((lane>>4)<<2);
  f16x4 lo = *(const f16x4*)p;
  f16x4 hi = *(const f16x4*)(p+16);
  return __builtin_shufflevector(lo, hi, 0,1,2,3,4,5,6,7);
}

__device__ __forceinline__ void init_acc(f32x4 acc[4],
                                         const float* __restrict__ bias, int wv, int lane){
#pragma unroll
  for (int i=0;i<4;++i){
    float bv = bias[wv*64 + i*16 + (lane&15)];
    acc[i] = (f32x4){bv,bv,bv,bv};
  }
}

// gates[16 rows][wave's 64 cols] += [A1|A2] * B_hi  (A_hi*B + A_lo*B)
template<int KT, int SPLIT>
__device__ __forceinline__ void gemm_stream(f32x4 acc[4],
    const f16x8* __restrict__ Bp,
    const f16* __restrict__ A1h, const f16* __restrict__ A1l,
    const f16* __restrict__ A2h, const f16* __restrict__ A2l,
    int wv, int lane)
{
  const int nb = wv*4;
  f16x8 Bc[4], Bn[4];
#pragma unroll
  for (int i=0;i<4;++i) Bc[i] = Bp[(nb + i)*64 + lane];
#pragma unroll
  for (int kt=0; kt<KT; ++kt){
    if (kt+1 < KT){
#pragma unroll
      for (int i=0;i<4;++i) Bn[i] = Bp[((kt+1)*32 + nb + i)*64 + lane];
    }
    f16x8 ah, al;
    if (kt < SPLIT){
      int kc = kt*32;
      ah = load_afrag<A1S>(A1h, kc, lane);
      al = load_afrag<A1S>(A1l, kc, lane);
    } else {
      int kc = (kt-SPLIT)*32;
      ah = load_afrag<A2S>(A2h, kc, lane);
      al = load_afrag<A2S>(A2l, kc, lane);
    }
#pragma unroll
    for (int i=0;i<4;++i){
      acc[i] = MFMA16(ah, Bc[i], acc[i]);
      acc[i] = MFMA16(al, Bc[i], acc[i]);
    }
#pragma unroll
    for (int i=0;i<4;++i) Bc[i] = Bn[i];
  }
}

// 4x4 transpose within a lane-quad
__device__ __forceinline__ void quad_transpose(float&a0,float&a1,float&a2,float&a3,int q){
  bool odd = (q & 1) != 0;
  float s0 = odd ? a0 : a1, s1 = odd ? a2 : a3;
  float r0 = __shfl_xor(s0,1), r1 = __shfl_xor(s1,1);
  float b0 = odd ? r0 : a0, b1 = odd ? a1 : r0;
  float b2 = odd ? r1 : a2, b3 = odd ? a3 : r1;
  bool hi = (q & 2) != 0;
  float u0 = hi ? b0 : b2, u1 = hi ? b1 : b3;
  float v0 = __shfl_xor(u0,2), v1 = __shfl_xor(u1,2);
  a0 = hi ? v0 : b0; a1 = hi ? v1 : b1;
  a2 = hi ? b2 : v0; a3 = hi ? b3 : v1;
}

template<int DSTRIDE>
__device__ __forceinline__ void lstm_update_m(f32x4 acc[4], float cr[4],
    f16* __restrict__ Dh, f16* __restrict__ Dl, int wv, int lane)
{
  const int q = lane & 3;
  const int rsub = ((lane>>4)<<2) + q;
  const int usub = wv*16 + ((lane&15)>>2);
#pragma unroll
  for (int nt=0;nt<4;++nt){
    float a0=acc[nt][0], a1=acc[nt][1], a2=acc[nt][2], a3=acc[nt][3];
    quad_transpose(a0,a1,a2,a3,q);
    float iv=fsig(a0), fv=fsig(a1), gv=ftanh(a2), ov=fsig(a3);
    float cn = fv*cr[nt] + iv*gv;
    cr[nt] = cn;
    float h = ov*ftanh(cn);
    f16 hh = (f16)h;
    f16 hl = (f16)(h - (float)hh);
    int off = rsub*DSTRIDE + usub + nt*4;
    Dh[off]=hh; Dl[off]=hl;
  }
}

__global__ void __launch_bounds__(512, 4)
lstm_main(const float* __restrict__ hist, float* __restrict__ ws,
          float* __restrict__ out)
{
  const f16* wh = (const f16*)ws;
  const float* wf = ws + FOFF;
  unsigned* bar = (unsigned*)(ws + FOFF + BAR_F);
  const f16x8* BE0 = (const f16x8*)(wh + HOFF_E0);
  const f16x8* BE1 = (const f16x8*)(wh + HOFF_E1);
  const f16x8* BD0 = (const f16x8*)(wh + HOFF_D0);
  const f16x8* BD1 = (const f16x8*)(wh + HOFF_D1);
  const f16x8* BH  = (const f16x8*)(wh + HOFF_H);

  __shared__ __align__(16) f16 A1h[BM*A1S], A1l[BM*A1S];
  __shared__ __align__(16) f16 A2h[BM*A2S], A2l[BM*A2S];
  __shared__ __align__(16) float o1buf[BM*O1S];

  const int tid  = threadIdx.x;
  const int wv   = tid >> 6;      // wave 0..7: gate cols [wv*64, wv*64+64)
  const int lane = tid & 63;
  const int b0   = blockIdx.x * BM;
  const int lidx = lane & 15;

  for (int i = tid; i < BM*A1S; i += 512){ A1h[i]=(f16)0.f; A1l[i]=(f16)0.f; }
  for (int i = tid; i < BM*A2S; i += 512){ A2h[i]=(f16)0.f; A2l[i]=(f16)0.f; }
  float c0r[4] = {0,0,0,0};
  float c1r[4] = {0,0,0,0};
  f32x4 acc[4];

  const int lr = tid/6, ld = tid - (tid/6)*6;   // hist loader (tid<96)

  if (tid < 96){
    float v = hist[(b0+lr)*768 + ld];
    f16 hv = (f16)v;
    A1h[lr*A1S + 128 + ld] = hv;
    A1l[lr*A1S + 128 + ld] = (f16)(v - (float)hv);
  }
  __syncthreads();

  // ------------------------- encoder: 128 steps ---------------------------
  for (int t=0; t<128; ++t){
    if ((t & 1) == 0) grid_pace(bar, t>>1, tid);   // lockstep (every 2 steps)

    init_acc(acc, wf + FB_E0, wv, lane);
    gemm_stream<5,99>(acc, BE0, A1h, A1l, A2h, A2l, wv, lane);
    __syncthreads();
    lstm_update_m<A1S>(acc, c0r, A1h, A1l, wv, lane);   // h0 -> A1[0..127]
    __syncthreads();

    init_acc(acc, wf + FB_E1, wv, lane);
    gemm_stream<8,4>(acc, BE1, A1h, A1l, A2h, A2l, wv, lane);
    __syncthreads();
    if (t < 127 && tid < 96){                    // hist(t+1): x-cols idle here
      float v = hist[(b0+lr)*768 + (t+1)*6 + ld];
      f16 hv = (f16)v;
      A1h[lr*A1S + 128 + ld] = hv;
      A1l[lr*A1S + 128 + ld] = (f16)(v - (float)hv);
    }
    lstm_update_m<A2S>(acc, c1r, A2h, A2l, wv, lane);   // h1 -> A2[0..127]
    __syncthreads();
  }

  // decoder seed: x = hist[:, -1, :2]; zero enc-only x cols 130..133
  if (tid < 32){
    int r = tid>>1, j = tid&1;
    float v = hist[(b0+r)*768 + 762 + j];
    f16 hv = (f16)v;
    A1h[r*A1S + 128 + j] = hv;
    A1l[r*A1S + 128 + j] = (f16)(v - (float)hv);
  } else if (tid < 96){
    int idx = tid - 32;
    int r = idx>>2, cl = 130 + (idx&3);
    A1h[r*A1S + cl] = (f16)0.f;
    A1l[r*A1S + cl] = (f16)0.f;
  }
  __syncthreads();

  // ------------------------- decoder: 125 steps ---------------------------
  for (int t=0; t<125; ++t){
    int gstep = 128 + t;
    if ((gstep & 1) == 0) grid_pace(bar, gstep>>1, tid);

    init_acc(acc, wf + FB_D0, wv, lane);
    gemm_stream<5,99>(acc, BD0, A1h, A1l, A2h, A2l, wv, lane);
    __syncthreads();
    lstm_update_m<A1S>(acc, c0r, A1h, A1l, wv, lane);
    __syncthreads();

    init_acc(acc, wf + FB_D1, wv, lane);
    gemm_stream<8,4>(acc, BD1, A1h, A1l, A2h, A2l, wv, lane);
    __syncthreads();
    lstm_update_m<A2S>(acc, c1r, A2h, A2l, wv, lane);
    __syncthreads();

    // head layer 1: relu(h1 @ W1^T + b1) -> o1 (fp32 LDS); wave wv = ntile wv
    {
      float bH1 = wf[FB_H1 + wv*16 + lidx];
      f32x4 ha = {bH1,bH1,bH1,bH1};
#pragma unroll
      for (int kt=0;kt<4;++kt){
        f16x8 Wc = BH[(kt*8 + wv)*64 + lane];
        int kc = kt*32;
        f16x8 ah = load_afrag<A2S>(A2h, kc, lane);
        f16x8 al = load_afrag<A2S>(A2l, kc, lane);
        ha = MFMA16(ah, Wc, ha);
        ha = MFMA16(al, Wc, ha);
      }
#pragma unroll
      for (int r=0;r<4;++r){
        float v = ha[r]; v = v > 0.f ? v : 0.f;
        int rr = ((lane>>4)<<2) + r;
        o1buf[rr*O1S + wv*16 + lidx] = v;
      }
    }
    __syncthreads();

    // head layer 2 + autoregressive feedback
    if (tid < 32){
      int r = tid>>1, j = tid&1;
      const float* op = o1buf + r*O1S;
      const float* w2 = wf + FB_W2 + j;
      float s0=0.f,s1=0.f,s2=0.f,s3=0.f;
#pragma unroll
      for (int k=0;k<128;k+=4){
        s0 = fmaf(op[k],   w2[2*k],   s0);
        s1 = fmaf(op[k+1], w2[2*k+2], s1);
        s2 = fmaf(op[k+2], w2[2*k+4], s2);
        s3 = fmaf(op[k+3], w2[2*k+6], s3);
      }
      float pred = wf[FB_B2 + j] + ((s0+s1)+(s2+s3));
      out[(b0+r)*250 + t*2 + j] = pred;
      f16 ph = (f16)pred;
      A1h[r*A1S + 128 + j] = ph;
      A1l[r*A1S + 128 + j] = (f16)(pred - (float)ph);
    }
    __syncthreads();
  }
}

// ---------------------------------------------------------------------------
// setup: pack B-hi weights into per-lane MFMA fragment order, biases fused +
// col-remapped, W2 transposed. col = unit*4 + gate; orig row = gate*128+unit.
// k element (lane,j): k = kt*32 + (j>=4?16:0) + (lane>>4)*4 + (j&3)
// (identical to rounds 5-10)
// ---------------------------------------------------------------------------
__global__ void setup_kernel(
    const float* __restrict__ eWih0, const float* __restrict__ eWhh0,
    const float* __restrict__ ebih0, const float* __restrict__ ebhh0,
    const float* __restrict__ eWih1, const float* __restrict__ eWhh1,
    const float* __restrict__ ebih1, const float* __restrict__ ebhh1,
    const float* __restrict__ dWih0, const float* __restrict__ dWhh0,
    const float* __restrict__ dbih0, const float* __restrict__ dbhh0,
    const float* __restrict__ dWih1, const float* __restrict__ dWhh1,
    const float* __restrict__ dbih1, const float* __restrict__ dbhh1,
    const float* __restrict__ W1, const float* __restrict__ b1,
    const float* __restrict__ W2, const float* __restrict__ b2,
    float* __restrict__ ws)
{
  int i = blockIdx.x*256 + threadIdx.x;
  if (i < H_TOTAL){
    f16* whp = (f16*)ws;
    const float *Wa, *Wb; int ka, kb, off; bool head = false;
    if      (i < HOFF_E1){ off=HOFF_E0; Wa=eWhh0; ka=128; Wb=eWih0; kb=6; }
    else if (i < HOFF_D0){ off=HOFF_E1; Wa=eWih1; ka=128; Wb=eWhh1; kb=128; }
    else if (i < HOFF_D1){ off=HOFF_D0; Wa=dWhh0; ka=128; Wb=dWih0; kb=2; }
    else if (i < HOFF_H) { off=HOFF_D1; Wa=dWih1; ka=128; Wb=dWhh1; kb=128; }
    else                 { off=HOFF_H;  Wa=W1; ka=128; Wb=W1; kb=0; head=true; }
    int local = i - off;
    int j     = local & 7;
    int lane  = (local>>3) & 63;
    int nk    = local >> 9;
    int NTl   = head ? 8 : 32;
    int n     = nk % NTl;
    int kt    = nk / NTl;
    int col   = n*16 + (lane&15);
    int koff  = ((j>>2)<<4) + ((lane>>4)<<2) + (j&3);
    int kin   = kt*32 + koff;
    float val;
    if (head){
      val = (kin < 128) ? W1[col*128 + kin] : 0.f;
    } else {
      int orow = (col&3)*128 + (col>>2);
      val = (kin < ka) ? Wa[orow*ka + kin]
          : ((kin < ka+kb) ? Wb[orow*kb + (kin-ka)] : 0.f);
    }
    whp[i] = (f16)val;
  } else if (i < H_TOTAL + F_TOTAL){
    int f = i - H_TOTAL;
    float* wfp = ws + FOFF;
    if (f < 2048){
      int layer = f >> 9, c = f & 511;
      int orow = (c&3)*128 + (c>>2);
      const float *bi, *bh;
      if      (layer==0){ bi=ebih0; bh=ebhh0; }
      else if (layer==1){ bi=ebih1; bh=ebhh1; }
      else if (layer==2){ bi=dbih0; bh=dbhh0; }
      else              { bi=dbih1; bh=dbhh1; }
      wfp[f] = bi[orow] + bh[orow];
    } else if (f < 2176){
      wfp[f] = b1[f-2048];
    } else if (f < 2432){
      int k = (f-2176)>>1, j = (f-2176)&1;
      wfp[f] = W2[j*128 + k];
    } else {
      wfp[f] = b2[f-2432];
    }
  }
}

extern "C" void kernel_launch(void* const* d_in, const int* in_sizes, int n_in,
                              void* d_out, int out_size, void* d_ws, size_t ws_size,
                              hipStream_t stream)
{
  const float* hist = (const float*)d_in[0];
  float* ws = (float*)d_ws;

  // zero the pacing-barrier counters (capture-safe async memset)
  (void)hipMemsetAsync((char*)d_ws + (FOFF + BAR_F)*4, 0, BAR_BYTES, stream);

  int total = H_TOTAL + F_TOTAL;
  setup_kernel<<<(total + 255)/256, 256, 0, stream>>>(
      (const float*)d_in[1],  (const float*)d_in[2],
      (const float*)d_in[3],  (const float*)d_in[4],
      (const float*)d_in[5],  (const float*)d_in[6],
      (const float*)d_in[7],  (const float*)d_in[8],
      (const float*)d_in[9],  (const float*)d_in[10],
      (const float*)d_in[11], (const float*)d_in[12],
      (const float*)d_in[13], (const float*)d_in[14],
      (const float*)d_in[15], (const float*)d_in[16],
      (const float*)d_in[17], (const float*)d_in[18],
      (const float*)d_in[19], (const float*)d_in[20],
      ws);

  lstm_main<<<NBLK, 512, 0, stream>>>(hist, ws, (float*)d_out);
}

// Round 13
// 3254.385 us; speedup vs baseline: 1.8799x; 1.8799x over previous
//
#include <hip/hip_runtime.h>

// ---------------------------------------------------------------------------
// LSTM autoregressive, MI355X. Round 13 (= r12 + compile fix: no pointer
// arrays into dynamic LDS; parity-offset arithmetic instead).
//  - r10 anchor kept: 256 blocks x 512 thr, launch_bounds(512,2) (the only
//    proven zero-spill/128-VGPR shape), BM=32, hi-only B 1-deep, lockstep L2
//  - LDS h0/h1/x double buffers (parity offset): gemm+update fuse; encoder
//    2 barriers/step (was 5), decoder 5 (was 7)
//  - group pacing: 8 counters, 32 blocks each (bid&7 ~ XCD round-robin)
//  - dynamic LDS 97.9 KB via hipFuncSetAttribute
// ---------------------------------------------------------------------------

typedef _Float16 f16;
typedef _Float16 f16x4 __attribute__((ext_vector_type(4)));
typedef _Float16 f16x8 __attribute__((ext_vector_type(8)));
typedef float    f32x4 __attribute__((ext_vector_type(4)));

#define MFMA16(a,b,c) __builtin_amdgcn_mfma_f32_16x16x32_f16((a),(b),(c),0,0,0)

#define BM 32
#define NBLK 256
#define PACE_TGT 32   // blocks per pace group (NBLK/8)

// ws layout: fp16 B-hi fragments (halves), then fp32 region (floats)
#define HOFF_E0 0
#define HOFF_E1 81920
#define HOFF_D0 212992
#define HOFF_D1 294912
#define HOFF_H  425984
#define H_TOTAL 442368
#define FOFF    221184
#define FB_E0 0
#define FB_E1 512
#define FB_D0 1024
#define FB_D1 1536
#define FB_H1 2048
#define FB_W2 2176
#define FB_B2 2432
#define F_TOTAL 2434
#define BAR_F   2560     // 253 steps x 8 groups u32
#define BAR_BYTES 8192

#define HS 140    // h row stride (halves): 70 dw, 6r%32 -> 2-way (free)
#define XS 36     // x row stride (halves): 18 dw -> 2-way (free)
#define O1S 133

// LDS base offsets in halves; parity buffer at base + c*stride
#define HBUF 4480         // 32*HS
#define XBUF 1152         // 32*XS
#define L_H0H 0           // +c*HBUF
#define L_H0L 8960
#define L_H1H 17920
#define L_H1L 26880
#define L_XH  35840       // +c*XBUF
#define L_XL  38144
#define L_HALVES 40448
#define LDS_BYTES 97920   // 80896 + 32*133*4

__device__ __forceinline__ float fsig(float x){ return 1.0f/(1.0f+__expf(-x)); }
__device__ __forceinline__ float ftanh(float x){
  float a = fabsf(x);
  float e = __expf(-2.0f*a);
  float t = (1.0f-e)/(1.0f+e);
  return x < 0.0f ? -t : t;
}

// group pacing barrier: pure performance device (lockstep weight streaming).
__device__ __forceinline__ void grid_pace(unsigned* __restrict__ bar, int idx, int g, int tid){
  __syncthreads();
  if (tid == 0){
    unsigned* p = &bar[idx*8 + g];
    __hip_atomic_fetch_add(p, 1u, __ATOMIC_RELAXED, __HIP_MEMORY_SCOPE_AGENT);
    while (__hip_atomic_load(p, __ATOMIC_RELAXED, __HIP_MEMORY_SCOPE_AGENT) < (unsigned)PACE_TGT)
      __builtin_amdgcn_s_sleep(1);
  }
  __syncthreads();
}

// A fragment: row = m*16 + (lane&15); k = kc + (lane>>4)*4 + j (+16 for j>=4)
template<int STRIDE>
__device__ __forceinline__ f16x8 load_afrag(const f16* buf, int m, int kc, int lane){
  const f16* p = buf + (m*16 + (lane&15))*STRIDE + kc + ((lane>>4)<<2);
  f16x4 lo = *(const f16x4*)p;
  f16x4 hi = *(const f16x4*)(p+16);
  return __builtin_shufflevector(lo, hi, 0,1,2,3,4,5,6,7);
}

__device__ __forceinline__ void init_acc(f32x4 acc[2][4],
                                         const float* __restrict__ bias, int wv, int lane){
#pragma unroll
  for (int i=0;i<4;++i){
    float bv = bias[wv*64 + i*16 + (lane&15)];
    f32x4 b4 = {bv,bv,bv,bv};
    acc[0][i]=b4; acc[1][i]=b4;
  }
}

// gates[32 rows][wave's 64 cols] += [A(SPLIT kt, stride HS) | C(rest, stride SB)] * B_hi
template<int KT, int SPLIT, int SB>
__device__ __forceinline__ void gemm2(f32x4 acc[2][4],
    const f16x8* __restrict__ Bp,
    const f16* __restrict__ Ah, const f16* __restrict__ Al,
    const f16* __restrict__ Ch, const f16* __restrict__ Cl,
    int wv, int lane)
{
  const int nb = wv*4;
  f16x8 Bc[4], Bn[4];
#pragma unroll
  for (int i=0;i<4;++i) Bc[i] = Bp[(nb + i)*64 + lane];
#pragma unroll
  for (int kt=0; kt<KT; ++kt){
    if (kt+1 < KT){
#pragma unroll
      for (int i=0;i<4;++i) Bn[i] = Bp[((kt+1)*32 + nb + i)*64 + lane];
    }
    f16x8 a0h,a0l,a1h,a1l;
    if (kt < SPLIT){
      int kc = kt*32;
      a0h = load_afrag<HS>(Ah, 0, kc, lane);
      a0l = load_afrag<HS>(Al, 0, kc, lane);
      a1h = load_afrag<HS>(Ah, 1, kc, lane);
      a1l = load_afrag<HS>(Al, 1, kc, lane);
    } else {
      int kc = (kt-SPLIT)*32;
      a0h = load_afrag<SB>(Ch, 0, kc, lane);
      a0l = load_afrag<SB>(Cl, 0, kc, lane);
      a1h = load_afrag<SB>(Ch, 1, kc, lane);
      a1l = load_afrag<SB>(Cl, 1, kc, lane);
    }
#pragma unroll
    for (int i=0;i<4;++i){
      acc[0][i] = MFMA16(a0h, Bc[i], acc[0][i]);
      acc[1][i] = MFMA16(a1h, Bc[i], acc[1][i]);
      acc[0][i] = MFMA16(a0l, Bc[i], acc[0][i]);
      acc[1][i] = MFMA16(a1l, Bc[i], acc[1][i]);
    }
#pragma unroll
    for (int i=0;i<4;++i) Bc[i] = Bn[i];
  }
}

// 4x4 transpose within a lane-quad
__device__ __forceinline__ void quad_transpose(float&a0,float&a1,float&a2,float&a3,int q){
  bool odd = (q & 1) != 0;
  float s0 = odd ? a0 : a1, s1 = odd ? a2 : a3;
  float r0 = __shfl_xor(s0,1), r1 = __shfl_xor(s1,1);
  float b0 = odd ? r0 : a0, b1 = odd ? a1 : r0;
  float b2 = odd ? r1 : a2, b3 = odd ? a3 : r1;
  bool hi = (q & 2) != 0;
  float u0 = hi ? b0 : b2, u1 = hi ? b1 : b3;
  float v0 = __shfl_xor(u0,2), v1 = __shfl_xor(u1,2);
  a0 = hi ? v0 : b0; a1 = hi ? v1 : b1;
  a2 = hi ? b2 : v0; a3 = hi ? b3 : v1;
}

__device__ __forceinline__ void lstm_update_m(f32x4 acc[2][4], float cr[2][4],
    f16* __restrict__ Dh, f16* __restrict__ Dl, int wv, int lane)
{
  const int q = lane & 3;
  const int rsub = ((lane>>4)<<2) + q;
  const int usub = wv*16 + ((lane&15)>>2);
#pragma unroll
  for (int mt=0;mt<2;++mt)
#pragma unroll
  for (int nt=0;nt<4;++nt){
    float a0=acc[mt][nt][0], a1=acc[mt][nt][1], a2=acc[mt][nt][2], a3=acc[mt][nt][3];
    quad_transpose(a0,a1,a2,a3,q);
    float iv=fsig(a0), fv=fsig(a1), gv=ftanh(a2), ov=fsig(a3);
    float cn = fv*cr[mt][nt] + iv*gv;
    cr[mt][nt] = cn;
    float h = ov*ftanh(cn);
    f16 hh = (f16)h;
    f16 hl = (f16)(h - (float)hh);
    int off = (mt*16 + rsub)*HS + usub + nt*4;
    Dh[off]=hh; Dl[off]=hl;
  }
}

__global__ void __launch_bounds__(512, 2)
lstm_main(const float* __restrict__ hist, float* __restrict__ ws,
          float* __restrict__ out)
{
  const f16* wh = (const f16*)ws;
  const float* wf = ws + FOFF;
  unsigned* bar = (unsigned*)(ws + FOFF + BAR_F);
  const f16x8* BE0 = (const f16x8*)(wh + HOFF_E0);
  const f16x8* BE1 = (const f16x8*)(wh + HOFF_E1);
  const f16x8* BD0 = (const f16x8*)(wh + HOFF_D0);
  const f16x8* BD1 = (const f16x8*)(wh + HOFF_D1);
  const f16x8* BH  = (const f16x8*)(wh + HOFF_H);

  extern __shared__ __align__(16) f16 smem[];
  float* o1buf = (float*)(smem + L_HALVES);

  const int tid  = threadIdx.x;
  const int wv   = tid >> 6;
  const int lane = tid & 63;
  const int b0   = blockIdx.x * BM;
  const int g    = blockIdx.x & 7;
  const int lidx = lane & 15;

  for (int i = tid; i < L_HALVES; i += 512) smem[i] = (f16)0.f;   // zero h+x bufs
  float c0r[2][4] = {{0,0,0,0},{0,0,0,0}};
  float c1r[2][4] = {{0,0,0,0},{0,0,0,0}};
  f32x4 acc[2][4];

  const int lr = tid/6, ld = tid - (tid/6)*6;   // hist loader (tid<192)

  __syncthreads();   // zeros visible before x(0) seed
  if (tid < 192){    // x(0) -> x buf parity 1 (t=0 reads c^1 = 1)
    float v = hist[(b0+lr)*768 + ld];
    f16 hv = (f16)v;
    smem[L_XH + XBUF + lr*XS + ld] = hv;
    smem[L_XL + XBUF + lr*XS + ld] = (f16)(v - (float)hv);
  }
  __syncthreads();

  // ---------------- encoder: 128 steps, 2 barriers/step ----------------
  for (int t=0; t<128; ++t){
    const int c  = t & 1;            // write parity
    const int hw = c*HBUF, hr = (c^1)*HBUF;
    const int xw = c*XBUF, xr = (c^1)*XBUF;

    // P1: gemm0(t) + x(t+1) load + upd0 -> h0[c]
    init_acc(acc, wf + FB_E0, wv, lane);
    gemm2<5,4,XS>(acc, BE0,
                  smem + L_H0H + hr, smem + L_H0L + hr,
                  smem + L_XH  + xr, smem + L_XL  + xr, wv, lane);
    if (t < 127 && tid < 192){
      float v = hist[(b0+lr)*768 + (t+1)*6 + ld];
      f16 hv = (f16)v;
      smem[L_XH + xw + lr*XS + ld] = hv;
      smem[L_XL + xw + lr*XS + ld] = (f16)(v - (float)hv);
    }
    lstm_update_m(acc, c0r, smem + L_H0H + hw, smem + L_H0L + hw, wv, lane);
    __syncthreads();

    // P2: gemm1(t) reads h0[c], h1[c^1]; upd1 -> h1[c]
    init_acc(acc, wf + FB_E1, wv, lane);
    gemm2<8,4,HS>(acc, BE1,
                  smem + L_H0H + hw, smem + L_H0L + hw,
                  smem + L_H1H + hr, smem + L_H1L + hr, wv, lane);
    lstm_update_m(acc, c1r, smem + L_H1H + hw, smem + L_H1L + hw, wv, lane);
    grid_pace(bar, t, g, tid);       // closes the step (sync+spin+sync)
  }

  // decoder seed: x = hist[:, -1, :2] -> x buf parity 1
  if (tid < 64){
    int r = tid>>1, j = tid&1;
    float v = hist[(b0+r)*768 + 762 + j];
    f16 hv = (f16)v;
    smem[L_XH + XBUF + r*XS + j] = hv;
    smem[L_XL + XBUF + r*XS + j] = (f16)(v - (float)hv);
  }
  __syncthreads();

  // ---------------- decoder: 125 steps, 5 barriers/step ----------------
  for (int t=0; t<125; ++t){
    const int c  = t & 1;
    const int hw = c*HBUF, hr = (c^1)*HBUF;
    const int xw = c*XBUF, xr = (c^1)*XBUF;

    // P1: gemm0 + upd0 -> h0[c]
    init_acc(acc, wf + FB_D0, wv, lane);
    gemm2<5,4,XS>(acc, BD0,
                  smem + L_H0H + hr, smem + L_H0L + hr,
                  smem + L_XH  + xr, smem + L_XL  + xr, wv, lane);
    lstm_update_m(acc, c0r, smem + L_H0H + hw, smem + L_H0L + hw, wv, lane);
    __syncthreads();

    // P2: gemm1 + upd1 -> h1[c]
    init_acc(acc, wf + FB_D1, wv, lane);
    gemm2<8,4,HS>(acc, BD1,
                  smem + L_H0H + hw, smem + L_H0L + hw,
                  smem + L_H1H + hr, smem + L_H1L + hr, wv, lane);
    lstm_update_m(acc, c1r, smem + L_H1H + hw, smem + L_H1L + hw, wv, lane);
    __syncthreads();

    // P3: head1: relu(h1(t) @ W1^T + b1) -> o1
    {
      const f16* h1wH = smem + L_H1H + hw;
      const f16* h1wL = smem + L_H1L + hw;
      float bH1 = wf[FB_H1 + wv*16 + lidx];
      f32x4 ha0 = {bH1,bH1,bH1,bH1};
      f32x4 ha1 = ha0;
#pragma unroll
      for (int kt=0;kt<4;++kt){
        f16x8 Wc = BH[(kt*8 + wv)*64 + lane];
        int kc = kt*32;
        f16x8 a0h = load_afrag<HS>(h1wH, 0, kc, lane);
        f16x8 a0l = load_afrag<HS>(h1wL, 0, kc, lane);
        f16x8 a1h = load_afrag<HS>(h1wH, 1, kc, lane);
        f16x8 a1l = load_afrag<HS>(h1wL, 1, kc, lane);
        ha0 = MFMA16(a0h, Wc, ha0);
        ha0 = MFMA16(a0l, Wc, ha0);
        ha1 = MFMA16(a1h, Wc, ha1);
        ha1 = MFMA16(a1l, Wc, ha1);
      }
#pragma unroll
      for (int r=0;r<4;++r){
        float v0 = ha0[r]; v0 = v0 > 0.f ? v0 : 0.f;
        float v1 = ha1[r]; v1 = v1 > 0.f ? v1 : 0.f;
        int rr = ((lane>>4)<<2) + r;
        o1buf[rr*O1S      + wv*16 + lidx] = v0;
        o1buf[(16+rr)*O1S + wv*16 + lidx] = v1;
      }
    }
    __syncthreads();

    // P4: head2 -> out + x(t+1) into x buf [c]
    if (tid < 64){
      int r = tid>>1, j = tid&1;
      const float* op = o1buf + r*O1S;
      const float* w2 = wf + FB_W2 + j;
      float s0=0.f,s1=0.f,s2=0.f,s3=0.f;
#pragma unroll
      for (int k=0;k<128;k+=4){
        s0 = fmaf(op[k],   w2[2*k],   s0);
        s1 = fmaf(op[k+1], w2[2*k+2], s1);
        s2 = fmaf(op[k+2], w2[2*k+4], s2);
        s3 = fmaf(op[k+3], w2[2*k+6], s3);
      }
      float pred = wf[FB_B2 + j] + ((s0+s1)+(s2+s3));
      out[(b0+r)*250 + t*2 + j] = pred;
      f16 ph = (f16)pred;
      smem[L_XH + xw + r*XS + j] = ph;
      smem[L_XL + xw + r*XS + j] = (f16)(pred - (float)ph);
    }
    grid_pace(bar, 128 + t, g, tid);
  }
}

// ---------------------------------------------------------------------------
// setup: identical packing to rounds 5-12
// ---------------------------------------------------------------------------
__global__ void setup_kernel(
    const float* __restrict__ eWih0, const float* __restrict__ eWhh0,
    const float* __restrict__ ebih0, const float* __restrict__ ebhh0,
    const float* __restrict__ eWih1, const float* __restrict__ eWhh1,
    const float* __restrict__ ebih1, const float* __restrict__ ebhh1,
    const float* __restrict__ dWih0, const float* __restrict__ dWhh0,
    const float* __restrict__ dbih0, const float* __restrict__ dbhh0,
    const float* __restrict__ dWih1, const float* __restrict__ dWhh1,
    const float* __restrict__ dbih1, const float* __restrict__ dbhh1,
    const float* __restrict__ W1, const float* __restrict__ b1,
    const float* __restrict__ W2, const float* __restrict__ b2,
    float* __restrict__ ws)
{
  int i = blockIdx.x*256 + threadIdx.x;
  if (i < H_TOTAL){
    f16* whp = (f16*)ws;
    const float *Wa, *Wb; int ka, kb, off; bool head = false;
    if      (i < HOFF_E1){ off=HOFF_E0; Wa=eWhh0; ka=128; Wb=eWih0; kb=6; }
    else if (i < HOFF_D0){ off=HOFF_E1; Wa=eWih1; ka=128; Wb=eWhh1; kb=128; }
    else if (i < HOFF_D1){ off=HOFF_D0; Wa=dWhh0; ka=128; Wb=dWih0; kb=2; }
    else if (i < HOFF_H) { off=HOFF_D1; Wa=dWih1; ka=128; Wb=dWhh1; kb=128; }
    else                 { off=HOFF_H;  Wa=W1; ka=128; Wb=W1; kb=0; head=true; }
    int local = i - off;
    int j     = local & 7;
    int lane  = (local>>3) & 63;
    int nk    = local >> 9;
    int NTl   = head ? 8 : 32;
    int n     = nk % NTl;
    int kt    = nk / NTl;
    int col   = n*16 + (lane&15);
    int koff  = ((j>>2)<<4) + ((lane>>4)<<2) + (j&3);
    int kin   = kt*32 + koff;
    float val;
    if (head){
      val = (kin < 128) ? W1[col*128 + kin] : 0.f;
    } else {
      int orow = (col&3)*128 + (col>>2);
      val = (kin < ka) ? Wa[orow*ka + kin]
          : ((kin < ka+kb) ? Wb[orow*kb + (kin-ka)] : 0.f);
    }
    whp[i] = (f16)val;
  } else if (i < H_TOTAL + F_TOTAL){
    int f = i - H_TOTAL;
    float* wfp = ws + FOFF;
    if (f < 2048){
      int layer = f >> 9, c = f & 511;
      int orow = (c&3)*128 + (c>>2);
      const float *bi, *bh;
      if      (layer==0){ bi=ebih0; bh=ebhh0; }
      else if (layer==1){ bi=ebih1; bh=ebhh1; }
      else if (layer==2){ bi=dbih0; bh=dbhh0; }
      else              { bi=dbih1; bh=dbhh1; }
      wfp[f] = bi[orow] + bh[orow];
    } else if (f < 2176){
      wfp[f] = b1[f-2048];
    } else if (f < 2432){
      int k = (f-2176)>>1, j = (f-2176)&1;
      wfp[f] = W2[j*128 + k];
    } else {
      wfp[f] = b2[f-2432];
    }
  }
}

extern "C" void kernel_launch(void* const* d_in, const int* in_sizes, int n_in,
                              void* d_out, int out_size, void* d_ws, size_t ws_size,
                              hipStream_t stream)
{
  const float* hist = (const float*)d_in[0];
  float* ws = (float*)d_ws;

  // raise dynamic-LDS cap (host-side attribute; capture-safe, idempotent)
  (void)hipFuncSetAttribute(reinterpret_cast<const void*>(lstm_main),
                            hipFuncAttributeMaxDynamicSharedMemorySize, LDS_BYTES);

  // zero the pacing-barrier counters (capture-safe async memset)
  (void)hipMemsetAsync((char*)d_ws + (size_t)(FOFF + BAR_F)*4, 0, BAR_BYTES, stream);

  int total = H_TOTAL + F_TOTAL;
  setup_kernel<<<(total + 255)/256, 256, 0, stream>>>(
      (const float*)d_in[1],  (const float*)d_in[2],
      (const float*)d_in[3],  (const float*)d_in[4],
      (const float*)d_in[5],  (const float*)d_in[6],
      (const float*)d_in[7],  (const float*)d_in[8],
      (const float*)d_in[9],  (const float*)d_in[10],
      (const float*)d_in[11], (const float*)d_in[12],
      (const float*)d_in[13], (const float*)d_in[14],
      (const float*)d_in[15], (const float*)d_in[16],
      (const float*)d_in[17], (const float*)d_in[18],
      (const float*)d_in[19], (const float*)d_in[20],
      ws);

  lstm_main<<<NBLK, 512, LDS_BYTES, stream>>>(hist, ws, (float*)d_out);
}